// Round 2
// baseline (278.064 us; speedup 1.0000x reference)
//
#include <hip/hip_runtime.h>
#include <math.h>

#define CH 85

// records per scale
static constexpr int RS = 16 * 76 * 76 * 3;   // 277248 (stride 8)
static constexpr int RM = 16 * 38 * 38 * 3;   //  69312 (stride 16)
static constexpr int RL = 16 * 19 * 19 * 3;   //  17328 (stride 32)

static constexpr int RECB = 128;              // records per block
static constexpr int BS_BLK = RS / RECB;                 // 2166 (exact)
static constexpr int BM_BLK = (RM + RECB - 1) / RECB;    // 542 (last block 64 recs)
static constexpr int BL_BLK = (RL + RECB - 1) / RECB;    // 136 (last block 48 recs)
static constexpr int NBLK   = BS_BLK + BM_BLK + BL_BLK;  // 2844

static constexpr int N4_FULL = RECB * CH / 4;            // 2720
static constexpr int K_FULL  = 10;                       // full 256-wide iters
static constexpr int TAIL_T  = N4_FULL - K_FULL * 256;   // 160

__constant__ float c_anchors[18] = {
    12.f, 16.f, 19.f, 36.f, 40.f, 28.f,        // s (stride 8)
    36.f, 75.f, 76.f, 55.f, 72.f, 146.f,       // m (stride 16)
    142.f, 110.f, 192.f, 243.f, 459.f, 401.f   // l (stride 32)
};

__device__ __forceinline__ float fast_rcp(float x) {
    return __builtin_amdgcn_rcpf(x);
}
__device__ __forceinline__ float sigm(float x) {
    return fast_rcp(1.f + __expf(-x));
}
__device__ __forceinline__ float softplusf(float x) {
    // log(1 + e^x), stable
    return fmaxf(x, 0.f) + __logf(1.f + __expf(-fabsf(x)));
}

// ---- software-pipeline stages: register-staged batch load / compute ----
// All arrays are static-indexed via full unroll (rule: no runtime-indexed
// ext arrays -> scratch). cbase/lbase are block-uniform (SGPR base).

template<int CNT>
__device__ __forceinline__ void load_stage(const float* __restrict__ cbase,
                                           const float* __restrict__ lbase,
                                           int nrec, const int (&i4s)[CNT],
                                           const bool (&act)[CNT],
                                           float4 (&cv)[CNT], float4 (&lv)[CNT],
                                           float (&ra)[CNT], float (&rb)[CNT])
{
    #pragma unroll
    for (int u = 0; u < CNT; ++u) {
        int e = i4s[u] << 2;
        cv[u] = *reinterpret_cast<const float4*>(cbase + e);
        lv[u] = *reinterpret_cast<const float4*>(lbase + e);
        unsigned rA  = (unsigned)e / 85u;                 // magic-mul
        unsigned rBi = rA + 1u;
        unsigned rmx = (unsigned)(nrec - 1);
        rBi = (rBi > rmx) ? rmx : rBi;                    // clamp (value unused when clamped)
        // near-uniform gathers (~4 distinct lines per wave, stream-hot)
        float a = lbase[rA * 85u + 4u];
        float b = lbase[rBi * 85u + 4u];
        ra[u] = act[u] ? a : 0.f;                         // tail gating -> adds 0
        rb[u] = act[u] ? b : 0.f;
    }
}

template<int CNT>
__device__ __forceinline__ void comp_stage(const int (&i4s)[CNT],
                                           const float4 (&cv)[CNT], const float4 (&lv)[CNT],
                                           const float (&ra)[CNT], const float (&rb)[CNT],
                                           float& prob_acc)
{
    #pragma unroll
    for (int u = 0; u < CNT; ++u) {
        int e = i4s[u] << 2;
        unsigned rA  = (unsigned)e / 85u;
        unsigned rem = (rA + 1u) * 85u - (unsigned)e;     // 1..85 floats left in record
        float respA = ra[u], respB = rb[u];
        float r1 = (rem <= 1u) ? respB : respA;
        float r2 = (rem <= 2u) ? respB : respA;
        float r3 = (rem <= 3u) ? respB : respA;
        prob_acc = fmaf(respA, fmaf(-lv[u].x, cv[u].x, softplusf(cv[u].x)), prob_acc);
        prob_acc = fmaf(r1,    fmaf(-lv[u].y, cv[u].y, softplusf(cv[u].y)), prob_acc);
        prob_acc = fmaf(r2,    fmaf(-lv[u].z, cv[u].z, softplusf(cv[u].z)), prob_acc);
        prob_acc = fmaf(r3,    fmaf(-lv[u].w, cv[u].w, softplusf(cv[u].w)), prob_acc);
    }
}

__global__ __launch_bounds__(256, 4) void yolo_main(
    const float* __restrict__ conv_l, const float* __restrict__ conv_m,
    const float* __restrict__ conv_s, const float* __restrict__ lab_s,
    const float* __restrict__ lab_m, const float* __restrict__ lab_l,
    const float* __restrict__ tb, float* __restrict__ pb)
{
    int blk = blockIdx.x;

    const float* conv; const float* lab;
    int S; float stride; int ao; int blkLocal; int nrec_scale;
    if (blk < BS_BLK) {
        conv = conv_s; lab = lab_s; S = 76; stride = 8.f;  ao = 0;
        blkLocal = blk;                 nrec_scale = RS;
    } else if (blk < BS_BLK + BM_BLK) {
        conv = conv_m; lab = lab_m; S = 38; stride = 16.f; ao = 6;
        blkLocal = blk - BS_BLK;        nrec_scale = RM;
    } else {
        conv = conv_l; lab = lab_l; S = 19; stride = 32.f; ao = 12;
        blkLocal = blk - BS_BLK - BM_BLK; nrec_scale = RL;
    }

    int r0   = blkLocal * RECB;
    int nrec = min(RECB, nrec_scale - r0);    // 128, 64 or 48 (always %4==0)
    int n4   = (nrec * CH) >> 2;

    const float* cbase = conv + (size_t)r0 * CH;   // 16B-aligned
    const float* lbase = lab  + (size_t)r0 * CH;

    int t = threadIdx.x;

    float prob_acc = 0.f, ciou_acc = 0.f, conf_acc = 0.f;
    // phase-2 per-record registers
    float c0 = 0.f, c1 = 0.f, c2v = 0.f, c3 = 0.f, c4 = 0.f;
    float l0 = 0.f, l1 = 0.f, l2 = 0.f, l3 = 0.f, resp = 0.f;

    if (n4 == N4_FULL) {
        // ---- deep-pipelined fast path: 3 register-staged batches ----
        int  iA[4] = { t,          t + 256,    t + 512,    t + 768  };
        int  iB[4] = { t + 1024,   t + 1280,   t + 1536,   t + 1792 };
        bool tl    = (t < TAIL_T);
        int  iC[3] = { t + 2048,   t + 2304,   tl ? (t + 2560) : t };
        bool a4[4] = { true, true, true, true };
        bool aC[3] = { true, true, tl };

        float4 cvA[4], lvA[4]; float raA[4], rbA[4];
        float4 cvB[4], lvB[4]; float raB[4], rbB[4];
        float4 cvC[3], lvC[3]; float raC[3], rbC[3];

        load_stage<4>(cbase, lbase, nrec, iA, a4, cvA, lvA, raA, rbA);
        load_stage<4>(cbase, lbase, nrec, iB, a4, cvB, lvB, raB, rbB);   // 16+16 loads in flight
        comp_stage<4>(iA, cvA, lvA, raA, rbA, prob_acc);
        load_stage<3>(cbase, lbase, nrec, iC, aC, cvC, lvC, raC, rbC);
        comp_stage<4>(iB, cvB, lvB, raB, rbB, prob_acc);
        // issue phase-2 gathers early: lines are L1/L2-hot from the stream;
        // latency hides under the last compute batch (issue-early/use-late)
        if (t < RECB) {
            const float* cr = cbase + t * CH;
            const float* lr = lbase + t * CH;
            c0 = cr[0]; c1 = cr[1]; c2v = cr[2]; c3 = cr[3]; c4 = cr[4];
            l0 = lr[0]; l1 = lr[1]; l2  = lr[2]; l3 = lr[3]; resp = lr[4];
        }
        comp_stage<3>(iC, cvC, lvC, raC, rbC, prob_acc);
    } else {
        // ---- partial blocks (only 2 of 2844): simple loop ----
        for (int i4 = t; i4 < n4; i4 += 256) {
            int e = i4 << 2;
            float4 cv = *reinterpret_cast<const float4*>(cbase + e);
            float4 lv = *reinterpret_cast<const float4*>(lbase + e);
            unsigned rA  = (unsigned)e / 85u;
            unsigned rem = (rA + 1u) * 85u - (unsigned)e;
            unsigned rBi = rA + 1u;
            unsigned rmx = (unsigned)(nrec - 1);
            rBi = (rBi > rmx) ? rmx : rBi;
            float respA = lbase[rA * 85u + 4u];
            float respB = lbase[rBi * 85u + 4u];
            float r1 = (rem <= 1u) ? respB : respA;
            float r2 = (rem <= 2u) ? respB : respA;
            float r3 = (rem <= 3u) ? respB : respA;
            prob_acc = fmaf(respA, fmaf(-lv.x, cv.x, softplusf(cv.x)), prob_acc);
            prob_acc = fmaf(r1,    fmaf(-lv.y, cv.y, softplusf(cv.y)), prob_acc);
            prob_acc = fmaf(r2,    fmaf(-lv.z, cv.z, softplusf(cv.z)), prob_acc);
            prob_acc = fmaf(r3,    fmaf(-lv.w, cv.w, softplusf(cv.w)), prob_acc);
        }
        if (t < nrec) {
            const float* cr = cbase + t * CH;
            const float* lr = lbase + t * CH;
            c0 = cr[0]; c1 = cr[1]; c2v = cr[2]; c3 = cr[3]; c4 = cr[4];
            l0 = lr[0]; l1 = lr[1]; l2  = lr[2]; l3 = lr[3]; resp = lr[4];
        }
    }

    // ---- phase 2: per-record box / conf ----
    if (t < nrec) {
        // subtract the spurious BCE that phase 1 added for channels 0..4
        // (identical formula on identical inputs; final reduce is double)
        float corr = fmaf(-l0,   c0,  softplusf(c0))
                   + fmaf(-l1,   c1,  softplusf(c1))
                   + fmaf(-l2,   c2v, softplusf(c2v))
                   + fmaf(-l3,   c3,  softplusf(c3))
                   + fmaf(-resp, c4,  softplusf(c4));
        prob_acc = fmaf(-resp, corr, prob_acc);

        unsigned rl = (unsigned)(r0 + t);
        unsigned a = rl % 3u; unsigned q = rl / 3u;
        unsigned j = q % (unsigned)S; q /= (unsigned)S;
        unsigned i = q % (unsigned)S; unsigned b = q / (unsigned)S;

        float lx = l0, ly = l1, lw = l2, lh = l3;

        // decode
        float px = (sigm(c0) + (float)j) * stride;
        float py = (sigm(c1) + (float)i) * stride;
        float pw = __expf(c2v) * c_anchors[ao + 2 * a];
        float ph = __expf(c3)  * c_anchors[ao + 2 * a + 1];

        // CIoU vs label
        float hx = 0.5f * pw, hy = 0.5f * ph;
        float b1x1 = px - hx, b1y1 = py - hy, b1x2 = px + hx, b1y2 = py + hy;
        float hlx = 0.5f * lw, hly = 0.5f * lh;
        float b2x1 = lx - hlx, b2y1 = ly - hly, b2x2 = lx + hlx, b2y2 = ly + hly;

        float area1 = (b1x2 - b1x1) * (b1y2 - b1y1);
        float area2 = (b2x2 - b2x1) * (b2y2 - b2y1);
        float lux = fmaxf(b1x1, b2x1), luy = fmaxf(b1y1, b2y1);
        float rdx = fminf(b1x2, b2x2), rdy = fminf(b1y2, b2y2);
        float iw = fmaxf(rdx - lux, 0.f), ih = fmaxf(rdy - luy, 0.f);
        float inter = iw * ih;
        float uni = area1 + area2 - inter;
        float iou = inter / (uni + 1e-9f);

        float encw = fmaxf(b1x2, b2x2) - fminf(b1x1, b2x1);
        float ench = fmaxf(b1y2, b2y2) - fminf(b1y1, b2y1);
        float cc2 = encw * encw + ench * ench;
        float dx = px - lx, dy = py - ly;
        float p2 = dx * dx + dy * dy;
        float at1 = atanf(pw / (ph + 1e-9f));
        float at2 = atanf(lw / (lh + 1e-9f));
        float dat = at1 - at2;
        const float FOUR_OVER_PI2 = 0.40528473456935109f;  // 4/pi^2
        float v = FOUR_OVER_PI2 * dat * dat;
        float al = v / (1.f - iou + v);
        float ciou = iou - p2 / cc2 - al * v;
        float bscale = 2.f - lw * lh * (1.f / (608.f * 608.f));
        ciou_acc = resp * bscale * (1.f - ciou);

        // conf loss: max IoU vs 70 true boxes of batch b
        const float4* tb4 = reinterpret_cast<const float4*>(tb) + (size_t)b * 70;
        float parea = pw * ph;
        float maxiou = 0.f;
        #pragma unroll 5
        for (int n = 0; n < 70; n++) {
            float4 tbx = tb4[n];
            float tx = tbx.x, ty = tbx.y, tw = tbx.z, th = tbx.w;
            float tx1 = tx - 0.5f * tw, ty1 = ty - 0.5f * th;
            float tx2 = tx + 0.5f * tw, ty2 = ty + 0.5f * th;
            float ix1 = fmaxf(b1x1, tx1), iy1 = fmaxf(b1y1, ty1);
            float ix2 = fminf(b1x2, tx2), iy2 = fminf(b1y2, ty2);
            float iiw = fmaxf(ix2 - ix1, 0.f), iih = fmaxf(iy2 - iy1, 0.f);
            float ia = iiw * iih;
            float u = parea + tw * th - ia;
            maxiou = fmaxf(maxiou, ia * fast_rcp(u));
        }
        float rbgd = (1.f - resp) * (maxiou < 0.5f ? 1.f : 0.f);
        // -log(sigm(x)+eps) ~= softplus(x)-x ; -log(1-sigm(x)+eps) ~= softplus(x)
        float spc = softplusf(c4);
        conf_acc = resp * (spc - c4) + rbgd * spc;
    }

    // ---- block reduce → per-block partials ----
    for (int off = 32; off > 0; off >>= 1) {
        ciou_acc += __shfl_down(ciou_acc, off);
        conf_acc += __shfl_down(conf_acc, off);
        prob_acc += __shfl_down(prob_acc, off);
    }
    __shared__ float red[4][3];
    int lane = threadIdx.x & 63, wv = threadIdx.x >> 6;
    if (lane == 0) { red[wv][0] = ciou_acc; red[wv][1] = conf_acc; red[wv][2] = prob_acc; }
    __syncthreads();
    if (threadIdx.x == 0) {
        pb[blk]            = red[0][0] + red[1][0] + red[2][0] + red[3][0];
        pb[NBLK + blk]     = red[0][1] + red[1][1] + red[2][1] + red[3][1];
        pb[2 * NBLK + blk] = red[0][2] + red[1][2] + red[2][2] + red[3][2];
    }
}

__global__ __launch_bounds__(256) void finalize_k(const float* __restrict__ pb,
                                                  float* __restrict__ out)
{
    double s0 = 0.0, s1 = 0.0, s2 = 0.0;
    for (int i = threadIdx.x; i < NBLK; i += 256) {
        s0 += (double)pb[i];
        s1 += (double)pb[NBLK + i];
        s2 += (double)pb[2 * NBLK + i];
    }
    for (int off = 32; off > 0; off >>= 1) {
        s0 += __shfl_down(s0, off);
        s1 += __shfl_down(s1, off);
        s2 += __shfl_down(s2, off);
    }
    __shared__ double rd[4][3];
    int lane = threadIdx.x & 63, wv = threadIdx.x >> 6;
    if (lane == 0) { rd[wv][0] = s0; rd[wv][1] = s1; rd[wv][2] = s2; }
    __syncthreads();
    if (threadIdx.x == 0) {
        float ci = (float)((rd[0][0] + rd[1][0] + rd[2][0] + rd[3][0]) / 16.0);
        float co = (float)((rd[0][1] + rd[1][1] + rd[2][1] + rd[3][1]) / 16.0);
        float pr = (float)((rd[0][2] + rd[1][2] + rd[2][2] + rd[3][2]) / 16.0);
        out[0] = ci + co + pr;
        out[1] = ci;
        out[2] = co;
        out[3] = pr;
    }
}

extern "C" void kernel_launch(void* const* d_in, const int* in_sizes, int n_in,
                              void* d_out, int out_size, void* d_ws, size_t ws_size,
                              hipStream_t stream) {
    const float* conv_l = (const float*)d_in[0];
    const float* conv_m = (const float*)d_in[1];
    const float* conv_s = (const float*)d_in[2];
    const float* lab_s  = (const float*)d_in[3];
    const float* lab_m  = (const float*)d_in[4];
    const float* lab_l  = (const float*)d_in[5];
    const float* tb     = (const float*)d_in[6];
    float* pb  = (float*)d_ws;   // 3*NBLK floats of partials
    float* out = (float*)d_out;

    yolo_main<<<NBLK, 256, 0, stream>>>(conv_l, conv_m, conv_s,
                                        lab_s, lab_m, lab_l, tb, pb);
    finalize_k<<<1, 256, 0, stream>>>(pb, out);
}

// Round 3
// 273.881 us; speedup vs baseline: 1.0153x; 1.0153x over previous
//
#include <hip/hip_runtime.h>
#include <math.h>

#define CH 85

// records per scale
static constexpr int RS = 16 * 76 * 76 * 3;   // 277248 (stride 8)
static constexpr int RM = 16 * 38 * 38 * 3;   //  69312 (stride 16)
static constexpr int RL = 16 * 19 * 19 * 3;   //  17328 (stride 32)
static constexpr int NREC = RS + RM + RL;     // 363888

// flat float4 index space over all conv/label elements
static constexpr unsigned N4S  = (unsigned)RS * 85u / 4u;        // 5,891,520
static constexpr unsigned N4M  = (unsigned)RM * 85u / 4u;        // 1,472,880
static constexpr unsigned N4SM = N4S + N4M;                      // 7,364,400
static constexpr unsigned N4T  = N4SM + (unsigned)RL * 85u / 4u; // 7,732,620

// stream family: 2048 blocks x 256 threads, grid-stride
static constexpr int NBLKA   = 2048;
static constexpr int THRA    = NBLKA * 256;                 // 524288
static constexpr int FULL_IT = (int)(N4T / (unsigned)THRA); // 14
static constexpr int REMA    = (int)(N4T - (unsigned)FULL_IT * (unsigned)THRA); // 392588

// record family: 1 thread per record
static constexpr int NBLKB    = (NREC + 255) / 256;  // 1422 (last block: 112 active)
static constexpr int NBLK_TOT = NBLKA + NBLKB;       // 3470

// partial-buffer layout in workspace
static constexpr int PB_CIOU = NBLKA;               // NBLKB entries
static constexpr int PB_CONF = NBLKA + NBLKB;       // NBLKB entries
static constexpr int PB_PRB2 = NBLKA + 2 * NBLKB;   // NBLKB entries (corr, negative)

__constant__ float c_anchors[18] = {
    12.f, 16.f, 19.f, 36.f, 40.f, 28.f,        // s (stride 8)
    36.f, 75.f, 76.f, 55.f, 72.f, 146.f,       // m (stride 16)
    142.f, 110.f, 192.f, 243.f, 459.f, 401.f   // l (stride 32)
};

__device__ __forceinline__ float fast_rcp(float x) {
    return __builtin_amdgcn_rcpf(x);
}
__device__ __forceinline__ float sigm(float x) {
    return fast_rcp(1.f + __expf(-x));
}
__device__ __forceinline__ float softplusf(float x) {
    // log(1 + e^x), stable
    return fmaxf(x, 0.f) + __logf(1.f + __expf(-fabsf(x)));
}

// BCE over one float4-pair; record-crossing handled branchlessly
__device__ __forceinline__ void bce4(const float* __restrict__ cb,
                                     const float* __restrict__ lb,
                                     unsigned el, unsigned rmax, float& acc)
{
    float4 cv = *reinterpret_cast<const float4*>(cb + el);
    float4 lv = *reinterpret_cast<const float4*>(lb + el);
    unsigned rA  = el / 85u;                      // magic-mul
    unsigned rem = (rA + 1u) * 85u - el;          // 1..85 floats left in record
    unsigned rB  = rA + 1u; if (rB > rmax) rB = rmax;   // OOB guard (value unused when clamped)
    float respA = lb[rA * 85u + 4u];              // near-uniform gather, stream-hot
    float respB = lb[rB * 85u + 4u];
    float r1 = (rem <= 1u) ? respB : respA;
    float r2 = (rem <= 2u) ? respB : respA;
    float r3 = (rem <= 3u) ? respB : respA;
    acc = fmaf(respA, fmaf(-lv.x, cv.x, softplusf(cv.x)), acc);
    acc = fmaf(r1,    fmaf(-lv.y, cv.y, softplusf(cv.y)), acc);
    acc = fmaf(r2,    fmaf(-lv.z, cv.z, softplusf(cv.z)), acc);
    acc = fmaf(r3,    fmaf(-lv.w, cv.w, softplusf(cv.w)), acc);
}

__global__ __launch_bounds__(256) void yolo_main(
    const float* __restrict__ conv_l, const float* __restrict__ conv_m,
    const float* __restrict__ conv_s, const float* __restrict__ lab_s,
    const float* __restrict__ lab_m, const float* __restrict__ lab_l,
    const float* __restrict__ tb, float* __restrict__ pb)
{
    int blk = blockIdx.x;
    int t   = threadIdx.x;

    float ciou_acc = 0.f, conf_acc = 0.f, prob_acc = 0.f;

    if (blk < NBLKA) {
        // ================= stream family: flat grid-stride BCE =================
        unsigned tid = (unsigned)(blk * 256 + t);

        auto proc = [&](unsigned i4) {
            const float* cb; const float* lb; unsigned el; unsigned rmax;
            if (i4 < N4S)       { cb = conv_s; lb = lab_s; el = i4 * 4u;          rmax = (unsigned)RS - 1u; }
            else if (i4 < N4SM) { cb = conv_m; lb = lab_m; el = (i4 - N4S) * 4u;  rmax = (unsigned)RM - 1u; }
            else                { cb = conv_l; lb = lab_l; el = (i4 - N4SM) * 4u; rmax = (unsigned)RL - 1u; }
            bce4(cb, lb, el, rmax, prob_acc);
        };

        #pragma unroll 4
        for (int k = 0; k < FULL_IT; ++k)
            proc(tid + (unsigned)k * (unsigned)THRA);
        if (tid < (unsigned)REMA)
            proc(tid + (unsigned)FULL_IT * (unsigned)THRA);
    } else {
        // ================= record family: 1 thread per record =================
        int g = (blk - NBLKA) * 256 + t;
        if (g < NREC) {
            const float* conv; const float* lab;
            int S; float stride; int ao; unsigned gl;
            if (g < RS) {
                conv = conv_s; lab = lab_s; S = 76; stride = 8.f;  ao = 0;  gl = (unsigned)g;
            } else if (g < RS + RM) {
                conv = conv_m; lab = lab_m; S = 38; stride = 16.f; ao = 6;  gl = (unsigned)(g - RS);
            } else {
                conv = conv_l; lab = lab_l; S = 19; stride = 32.f; ao = 12; gl = (unsigned)(g - RS - RM);
            }
            const float* cr = conv + (size_t)gl * CH;
            const float* lr = lab  + (size_t)gl * CH;
            float c0 = cr[0], c1 = cr[1], c2v = cr[2], c3 = cr[3], c4 = cr[4];
            float l0 = lr[0], l1 = lr[1], l2  = lr[2], l3 = lr[3], resp = lr[4];

            // subtract the spurious BCE the stream family added for channels 0..4
            float corr = fmaf(-l0,   c0,  softplusf(c0))
                       + fmaf(-l1,   c1,  softplusf(c1))
                       + fmaf(-l2,   c2v, softplusf(c2v))
                       + fmaf(-l3,   c3,  softplusf(c3))
                       + fmaf(-resp, c4,  softplusf(c4));
            prob_acc = -resp * corr;

            unsigned a = gl % 3u; unsigned q = gl / 3u;
            unsigned j = q % (unsigned)S; q /= (unsigned)S;
            unsigned i = q % (unsigned)S; unsigned b = q / (unsigned)S;

            float lx = l0, ly = l1, lw = l2, lh = l3;

            // decode
            float px = (sigm(c0) + (float)j) * stride;
            float py = (sigm(c1) + (float)i) * stride;
            float pw = __expf(c2v) * c_anchors[ao + 2 * a];
            float ph = __expf(c3)  * c_anchors[ao + 2 * a + 1];

            // CIoU vs label
            float hx = 0.5f * pw, hy = 0.5f * ph;
            float b1x1 = px - hx, b1y1 = py - hy, b1x2 = px + hx, b1y2 = py + hy;
            float hlx = 0.5f * lw, hly = 0.5f * lh;
            float b2x1 = lx - hlx, b2y1 = ly - hly, b2x2 = lx + hlx, b2y2 = ly + hly;

            float area1 = (b1x2 - b1x1) * (b1y2 - b1y1);
            float area2 = (b2x2 - b2x1) * (b2y2 - b2y1);
            float lux = fmaxf(b1x1, b2x1), luy = fmaxf(b1y1, b2y1);
            float rdx = fminf(b1x2, b2x2), rdy = fminf(b1y2, b2y2);
            float iw = fmaxf(rdx - lux, 0.f), ih = fmaxf(rdy - luy, 0.f);
            float inter = iw * ih;
            float uni = area1 + area2 - inter;
            float iou = inter / (uni + 1e-9f);

            float encw = fmaxf(b1x2, b2x2) - fminf(b1x1, b2x1);
            float ench = fmaxf(b1y2, b2y2) - fminf(b1y1, b2y1);
            float cc2 = encw * encw + ench * ench;
            float dx = px - lx, dy = py - ly;
            float p2 = dx * dx + dy * dy;
            float at1 = atanf(pw / (ph + 1e-9f));
            float at2 = atanf(lw / (lh + 1e-9f));
            float dat = at1 - at2;
            const float FOUR_OVER_PI2 = 0.40528473456935109f;  // 4/pi^2
            float v = FOUR_OVER_PI2 * dat * dat;
            float al = v / (1.f - iou + v);
            float ciou = iou - p2 / cc2 - al * v;
            float bscale = 2.f - lw * lh * (1.f / (608.f * 608.f));
            ciou_acc = resp * bscale * (1.f - ciou);

            // conf loss: max IoU vs 70 true boxes of batch b
            const float4* tb4 = reinterpret_cast<const float4*>(tb) + (size_t)b * 70;
            float parea = pw * ph;
            float maxiou = 0.f;
            #pragma unroll 5
            for (int n = 0; n < 70; n++) {
                float4 tbx = tb4[n];
                float tx = tbx.x, ty = tbx.y, tw = tbx.z, th = tbx.w;
                float tx1 = tx - 0.5f * tw, ty1 = ty - 0.5f * th;
                float tx2 = tx + 0.5f * tw, ty2 = ty + 0.5f * th;
                float ix1 = fmaxf(b1x1, tx1), iy1 = fmaxf(b1y1, ty1);
                float ix2 = fminf(b1x2, tx2), iy2 = fminf(b1y2, ty2);
                float iiw = fmaxf(ix2 - ix1, 0.f), iih = fmaxf(iy2 - iy1, 0.f);
                float ia = iiw * iih;
                float u = parea + tw * th - ia;
                maxiou = fmaxf(maxiou, ia * fast_rcp(u));
            }
            float rbgd = (1.f - resp) * (maxiou < 0.5f ? 1.f : 0.f);
            float spc = softplusf(c4);
            conf_acc = resp * (spc - c4) + rbgd * spc;
        }
    }

    // ---- block reduce → per-block partials ----
    for (int off = 32; off > 0; off >>= 1) {
        ciou_acc += __shfl_down(ciou_acc, off);
        conf_acc += __shfl_down(conf_acc, off);
        prob_acc += __shfl_down(prob_acc, off);
    }
    __shared__ float red[4][3];
    int lane = threadIdx.x & 63, wv = threadIdx.x >> 6;
    if (lane == 0) { red[wv][0] = ciou_acc; red[wv][1] = conf_acc; red[wv][2] = prob_acc; }
    __syncthreads();
    if (threadIdx.x == 0) {
        float pr = red[0][2] + red[1][2] + red[2][2] + red[3][2];
        if (blk < NBLKA) {
            pb[blk] = pr;
        } else {
            int gb = blk - NBLKA;
            pb[PB_CIOU + gb] = red[0][0] + red[1][0] + red[2][0] + red[3][0];
            pb[PB_CONF + gb] = red[0][1] + red[1][1] + red[2][1] + red[3][1];
            pb[PB_PRB2 + gb] = pr;
        }
    }
}

__global__ __launch_bounds__(256) void finalize_k(const float* __restrict__ pb,
                                                  float* __restrict__ out)
{
    double s0 = 0.0, s1 = 0.0, s2 = 0.0;
    for (int i = threadIdx.x; i < NBLKA; i += 256)
        s2 += (double)pb[i];                       // stream prob
    for (int i = threadIdx.x; i < NBLKB; i += 256) {
        s0 += (double)pb[PB_CIOU + i];
        s1 += (double)pb[PB_CONF + i];
        s2 += (double)pb[PB_PRB2 + i];             // prob correction (negative)
    }
    for (int off = 32; off > 0; off >>= 1) {
        s0 += __shfl_down(s0, off);
        s1 += __shfl_down(s1, off);
        s2 += __shfl_down(s2, off);
    }
    __shared__ double rd[4][3];
    int lane = threadIdx.x & 63, wv = threadIdx.x >> 6;
    if (lane == 0) { rd[wv][0] = s0; rd[wv][1] = s1; rd[wv][2] = s2; }
    __syncthreads();
    if (threadIdx.x == 0) {
        float ci = (float)((rd[0][0] + rd[1][0] + rd[2][0] + rd[3][0]) / 16.0);
        float co = (float)((rd[0][1] + rd[1][1] + rd[2][1] + rd[3][1]) / 16.0);
        float pr = (float)((rd[0][2] + rd[1][2] + rd[2][2] + rd[3][2]) / 16.0);
        out[0] = ci + co + pr;
        out[1] = ci;
        out[2] = co;
        out[3] = pr;
    }
}

extern "C" void kernel_launch(void* const* d_in, const int* in_sizes, int n_in,
                              void* d_out, int out_size, void* d_ws, size_t ws_size,
                              hipStream_t stream) {
    const float* conv_l = (const float*)d_in[0];
    const float* conv_m = (const float*)d_in[1];
    const float* conv_s = (const float*)d_in[2];
    const float* lab_s  = (const float*)d_in[3];
    const float* lab_m  = (const float*)d_in[4];
    const float* lab_l  = (const float*)d_in[5];
    const float* tb     = (const float*)d_in[6];
    float* pb  = (float*)d_ws;   // NBLKA + 3*NBLKB floats of partials
    float* out = (float*)d_out;

    yolo_main<<<NBLK_TOT, 256, 0, stream>>>(conv_l, conv_m, conv_s,
                                            lab_s, lab_m, lab_l, tb, pb);
    finalize_k<<<1, 256, 0, stream>>>(pb, out);
}